// Round 15
// baseline (153.452 us; speedup 1.0000x reference)
//
#include <hip/hip_runtime.h>
#include <hip/hip_fp16.h>
#include <stdint.h>
#include <math.h>

#define KB 512
#define KT 2048
#define KS 16
#define KPD 4
#define QT 512          // timesteps per quarter
#define NQ (KT / QT)
#define NWV 8           // waves per block
#define HRS 168         // f16 per H row (16B-aligned rows; 2-way-free fb reads)
#define QSTR 516        // u32 stride of QRl rows (spreads epilogue-store banks)

typedef _Float16 f16;
typedef _Float16 f16x8 __attribute__((ext_vector_type(8)));
typedef float f32x4 __attribute__((ext_vector_type(4)));

#define MFMA16(A, B, C) __builtin_amdgcn_mfma_f32_16x16x32_f16(A, B, C, 0, 0, 0)

__device__ __forceinline__ float softplus_f(float x) {
    float ax = fabsf(x);
    float e  = __expf(-ax);
    return fmaxf(x, 0.0f) + __logf(1.0f + e);
}
__device__ __forceinline__ float sigmoid_f(float x) {
    return __builtin_amdgcn_rcpf(1.0f + __expf(-x));
}
__device__ __forceinline__ float h2f_lo(uint32_t w) {
    return __half2float(__ushort_as_half((unsigned short)(w & 0xffffu)));
}
__device__ __forceinline__ float h2f_hi(uint32_t w) {
    return __half2float(__ushort_as_half((unsigned short)(w >> 16)));
}
__device__ __forceinline__ f16x8 zero8() {
    f16x8 v;
#pragma unroll
    for (int i = 0; i < 8; ++i) v[i] = (f16)0;
    return v;
}

// ---------------- fused kernel: block = one b; MLP (MFMA) + scan per quarter ----------------
__global__ __launch_bounds__(512, 4) void kalman_one(
    const float* __restrict__ z, const float* __restrict__ p,
    const float* __restrict__ mu0, const float* __restrict__ P0,
    const float* __restrict__ Wq1, const float* __restrict__ bq1,
    const float* __restrict__ Wq2, const float* __restrict__ bq2,
    const float* __restrict__ Wr1, const float* __restrict__ br1,
    const float* __restrict__ Wr2, const float* __restrict__ br2,
    const float* __restrict__ Wg1, const float* __restrict__ bg1,
    const float* __restrict__ Wg2, const float* __restrict__ bg2,
    float* __restrict__ out)
{
    __shared__ __align__(16) uint32_t QRl[KS * QSTR];            // 33024 B, [s][t-in-quarter]
    __shared__ __align__(16) float    Gl[QT];                    //  2048 B
    __shared__ __align__(16) uint32_t Ubuf[(NWV * KS * HRS) / 2]; // 43008 B: H slices (A) / zmu (B-D)

    const int tid = threadIdx.x;
    const int wv = tid >> 6;
    const int l = tid & 63;
    const int g = l >> 4;
    const int c = l & 15;
    const int b = blockIdx.x;

    f16* __restrict__ Hw = reinterpret_cast<f16*>(Ubuf) + wv * (KS * HRS);
    float* __restrict__ zmu = reinterpret_cast<float*>(Ubuf);

    const float* __restrict__ zb = z + (size_t)b * KT * KS;
    const float* __restrict__ pb = p + (size_t)b * KT * KPD;
    float* __restrict__ ob = out + (size_t)b * KT * KS;

    // ---- const A-frags: W1cat^T, 10 M-tiles (A[row=hcol][k=pd], k>=4 zero) ----
    f16x8 fA1[10];
#pragma unroll
    for (int m = 0; m < 10; ++m) {
        const float* W = (m < 4) ? (Wq1 + m * 16)
                       : (m < 8) ? (Wr1 + (m - 4) * 16)
                                 : (Wg1 + (m - 8) * 16);
        const int ld = (m < 8) ? 64 : 32;
        float w0 = W[0 * ld + c], w1 = W[1 * ld + c],
              w2 = W[2 * ld + c], w3 = W[3 * ld + c];
        f16x8 a = zero8();
        if (g == 0) { a[0] = (f16)w0; a[1] = (f16)w1; a[2] = (f16)w2; a[3] = (f16)w3; }
        fA1[m] = a;
    }
    // ---- const A-frags: W2cat^T ----
    f16x8 fA2[5];
#pragma unroll
    for (int i = 0; i < 4; ++i) {
        const float* W = (i < 2) ? Wq2 : Wr2;
        const int kb = (i & 1) * 32;
        f16x8 a;
#pragma unroll
        for (int j = 0; j < 8; ++j) a[j] = (f16)W[(kb + g * 8 + j) * 16 + c];
        fA2[i] = a;
    }
    {
        f16x8 a = zero8();
        if (c == 0) {
#pragma unroll
            for (int j = 0; j < 8; ++j) a[j] = (f16)Wg2[g * 8 + j];
        }
        fA2[4] = a;
    }
    const float bQ0 = bq2[g * 4 + 0], bQ1 = bq2[g * 4 + 1],
                bQ2 = bq2[g * 4 + 2], bQ3 = bq2[g * 4 + 3];
    const float bR0 = br2[g * 4 + 0], bR1 = br2[g * 4 + 1],
                bR2 = br2[g * 4 + 2], bR3 = br2[g * 4 + 3];
    const float bG = bg2[0];

    // ---- scan carries: wave wv owns chains s=wv and s=wv+8 ----
    float muA = mu0[b * KS + wv],     PA = P0[b * KS + wv];
    float muB = mu0[b * KS + wv + 8], PB = P0[b * KS + wv + 8];

    // per-s chunk scan (reads QRl/Gl/zmu, writes mu into zmu column s)
    auto scan_s = [&](int s, float& mu_q, float& P_q) {
        uint32_t qr[8];
        const uint32_t* qrow = QRl + (size_t)s * QSTR;
#pragma unroll
        for (int i = 0; i < 8; ++i) qr[i] = qrow[l * 8 + i];
        float c00 = 1.f, c01 = 0.f, c10 = 0.f, c11 = 1.f;
#pragma unroll
        for (int i = 0; i < 8; ++i) {
            float Q = h2f_lo(qr[i]), R = h2f_hi(qr[i]);
            float ta = fmaf(Q, c10, c00);
            float tb = fmaf(Q, c11, c01);
            float n10 = fmaf(Q + R, c10, c00);
            float n11 = fmaf(Q + R, c11, c01);
            c00 = R * ta; c01 = R * tb; c10 = n10; c11 = n11;
        }
        float rn = __builtin_amdgcn_rcpf(c11);
        float ma = c00 * rn, mb = c01 * rn, mc = c10 * rn;
#pragma unroll
        for (int r = 0; r < 6; ++r) {
            const int d = 1 << r;
            float pa = __shfl_up(ma, d);
            float pbv = __shfl_up(mb, d);
            float pc = __shfl_up(mc, d);
            float na = fmaf(ma, pa, mb * pc);
            float nb = fmaf(ma, pbv, mb);
            float nc = fmaf(mc, pa, pc);
            float nd = fmaf(mc, pbv, 1.f);
            float rr = __builtin_amdgcn_rcpf(nd);
            bool act = (l >= d);
            ma = act ? na * rr : ma;
            mb = act ? nb * rr : mb;
            mc = act ? nc * rr : mc;
        }
        float ea = __shfl_up(ma, 1);
        float eb = __shfl_up(mb, 1);
        float ec = __shfl_up(mc, 1);
        if (l == 0) { ea = 1.f; eb = 0.f; ec = 0.f; }
        float P = fmaf(ea, P_q, eb) * __builtin_amdgcn_rcpf(fmaf(ec, P_q, 1.f));

        float av[8], bw[8];
        float A = 1.f, Bv = 0.f;
#pragma unroll
        for (int i = 0; i < 8; ++i) {
            float Q = h2f_lo(qr[i]), R = h2f_hi(qr[i]);
            float Pp = P + Q;
            float K0 = Pp * __builtin_amdgcn_rcpf(Pp + R);
            float Kk = __builtin_amdgcn_fmed3f(K0, 1e-6f, 0.95f);
            int t = l * 8 + i;
            float gv = Gl[t];
            float gk = gv * Kk;
            float zv = zmu[t * 17 + s];
            av[i] = 1.f - gk;
            bw[i] = gk * zv;
            P = fmaf(-Kk, Pp, Pp);
            A = A * av[i];
            Bv = fmaf(av[i], Bv, bw[i]);
        }
        float P_end = __shfl(P, 63);
#pragma unroll
        for (int r = 0; r < 6; ++r) {
            const int d = 1 << r;
            float pA = __shfl_up(A, d);
            float pB = __shfl_up(Bv, d);
            float nA = A * pA;
            float nB = fmaf(A, pB, Bv);
            bool act = (l >= d);
            A  = act ? nA : A;
            Bv = act ? nB : Bv;
        }
        float eA = __shfl_up(A, 1);
        float eB = __shfl_up(Bv, 1);
        if (l == 0) { eA = 1.f; eB = 0.f; }
        float mu = fmaf(eA, mu_q, eB);
#pragma unroll
        for (int i = 0; i < 8; ++i) {
            mu = fmaf(av[i], mu, bw[i]);
            zmu[(l * 8 + i) * 17 + s] = mu;
        }
        mu_q = __shfl(mu, 63);
        P_q = P_end;
    };

    for (int q = 0; q < NQ; ++q) {
        // ============ phase A: MLP for this quarter (wave wv -> rows wv*64..+63) ============
        {
            const int trow = q * QT + wv * 64;
            const float4 pv = *reinterpret_cast<const float4*>(pb + (size_t)(trow + l) * KPD);

            f16x8 fBP[4];
#pragma unroll
            for (int n = 0; n < 4; ++n) {
                const int src = n * 16 + c;
                float x = __shfl(pv.x, src);
                float y = __shfl(pv.y, src);
                float zz = __shfl(pv.z, src);
                float w = __shfl(pv.w, src);
                f16x8 v = zero8();
                if (g == 0) { v[0] = (f16)x; v[1] = (f16)y; v[2] = (f16)zz; v[3] = (f16)w; }
                fBP[n] = v;
            }

#pragma unroll
            for (int n = 0; n < 4; ++n) {
                // GEMM1: 10 MFMA, relu+pack -> Hw (compiler orders DS deps)
#pragma unroll
                for (int m = 0; m < 10; ++m) {
                    const float* bs = (m < 4) ? (bq1 + m * 16)
                                    : (m < 8) ? (br1 + (m - 4) * 16)
                                              : (bg1 + (m - 8) * 16);
                    f32x4 acc;
                    acc[0] = bs[g * 4 + 0]; acc[1] = bs[g * 4 + 1];
                    acc[2] = bs[g * 4 + 2]; acc[3] = bs[g * 4 + 3];
                    acc = MFMA16(fA1[m], fBP[n], acc);
                    auto h01 = __builtin_amdgcn_cvt_pkrtz(fmaxf(acc[0], 0.f), fmaxf(acc[1], 0.f));
                    auto h23 = __builtin_amdgcn_cvt_pkrtz(fmaxf(acc[2], 0.f), fmaxf(acc[3], 0.f));
                    uint32_t w0, w1;
                    __builtin_memcpy(&w0, &h01, 4);
                    __builtin_memcpy(&w1, &h23, 4);
                    *reinterpret_cast<uint32_t*>(&Hw[c * HRS + m * 16 + g * 4 + 0]) = w0;
                    *reinterpret_cast<uint32_t*>(&Hw[c * HRS + m * 16 + g * 4 + 2]) = w1;
                }
                // GEMM2
                f16x8 fb0 = *reinterpret_cast<const f16x8*>(&Hw[c * HRS + 0 * 32 + g * 8]);
                f16x8 fb1 = *reinterpret_cast<const f16x8*>(&Hw[c * HRS + 1 * 32 + g * 8]);
                f16x8 fb2 = *reinterpret_cast<const f16x8*>(&Hw[c * HRS + 2 * 32 + g * 8]);
                f16x8 fb3 = *reinterpret_cast<const f16x8*>(&Hw[c * HRS + 3 * 32 + g * 8]);
                f16x8 fb4 = *reinterpret_cast<const f16x8*>(&Hw[c * HRS + 4 * 32 + g * 8]);

                f32x4 aq; aq[0] = bQ0; aq[1] = bQ1; aq[2] = bQ2; aq[3] = bQ3;
                aq = MFMA16(fA2[0], fb0, aq);
                aq = MFMA16(fA2[1], fb1, aq);
                f32x4 ar; ar[0] = bR0; ar[1] = bR1; ar[2] = bR2; ar[3] = bR3;
                ar = MFMA16(fA2[2], fb2, ar);
                ar = MFMA16(fA2[3], fb3, ar);
                f32x4 ag; ag[0] = 0.f; ag[1] = 0.f; ag[2] = 0.f; ag[3] = 0.f;
                ag = MFMA16(fA2[4], fb4, ag);

                uint32_t* qdst = QRl + (size_t)(g * 4) * QSTR + wv * 64 + n * 16 + c;
#pragma unroll
                for (int i = 0; i < 4; ++i) {
                    float Qv = softplus_f(aq[i]) + 1e-8f;
                    float Rv = softplus_f(ar[i]) + 1e-8f;
                    auto pk = __builtin_amdgcn_cvt_pkrtz(Qv, Rv);
                    uint32_t w; __builtin_memcpy(&w, &pk, 4);
                    qdst[(size_t)i * QSTR] = w;
                }
                if (g == 0)
                    Gl[wv * 64 + n * 16 + c] = sigmoid_f(ag[0] + bG);
            }
        }
        __syncthreads();   // QR/Gl ready; H region dead -> reusable as zmu

        // ============ phase B: stage z quarter into zmu ============
        {
            const float4* zq = reinterpret_cast<const float4*>(zb + (size_t)q * QT * KS);
#pragma unroll
            for (int v = 0; v < 4; ++v) {
                int k = tid + 512 * v;
                float4 w = zq[k];
                int t = k >> 2, s0 = (k & 3) << 2;
                zmu[t * 17 + s0 + 0] = w.x;
                zmu[t * 17 + s0 + 1] = w.y;
                zmu[t * 17 + s0 + 2] = w.z;
                zmu[t * 17 + s0 + 3] = w.w;
            }
        }
        __syncthreads();

        // ============ phase C: chunk scans (2 s-chains per wave) ============
        scan_s(wv, muA, PA);
        scan_s(wv + 8, muB, PB);
        __syncthreads();

        // ============ phase D: coalesced out store ============
        {
            float* od = ob + (size_t)q * QT * KS;
#pragma unroll
            for (int v = 0; v < 4; ++v) {
                int k = tid + 512 * v;
                int t = k >> 2, s0 = (k & 3) << 2;
                float4 w;
                w.x = zmu[t * 17 + s0 + 0];
                w.y = zmu[t * 17 + s0 + 1];
                w.z = zmu[t * 17 + s0 + 2];
                w.w = zmu[t * 17 + s0 + 3];
                *reinterpret_cast<float4*>(od + 4 * (size_t)k) = w;
            }
        }
        __syncthreads();   // zmu/H region reused next quarter
    }
}

// ---------------- launcher ----------------
extern "C" void kernel_launch(void* const* d_in, const int* in_sizes, int n_in,
                              void* d_out, int out_size, void* d_ws, size_t ws_size,
                              hipStream_t stream) {
    const float* z   = (const float*)d_in[0];
    const float* p   = (const float*)d_in[1];
    const float* mu0 = (const float*)d_in[2];
    const float* P0  = (const float*)d_in[3];
    const float* Wq1 = (const float*)d_in[4];
    const float* bq1 = (const float*)d_in[5];
    const float* Wq2 = (const float*)d_in[6];
    const float* bq2 = (const float*)d_in[7];
    const float* Wr1 = (const float*)d_in[8];
    const float* br1 = (const float*)d_in[9];
    const float* Wr2 = (const float*)d_in[10];
    const float* br2 = (const float*)d_in[11];
    const float* Wg1 = (const float*)d_in[12];
    const float* bg1 = (const float*)d_in[13];
    const float* Wg2 = (const float*)d_in[14];
    const float* bg2 = (const float*)d_in[15];
    float* out = (float*)d_out;

    hipLaunchKernelGGL(kalman_one, dim3(KB), dim3(512), 0, stream,
                       z, p, mu0, P0, Wq1, bq1, Wq2, bq2,
                       Wr1, br1, Wr2, br2, Wg1, bg1, Wg2, bg2, out);
}

// Round 16
// 86.579 us; speedup vs baseline: 1.7724x; 1.7724x over previous
//
#include <hip/hip_runtime.h>
#include <hip/hip_fp16.h>
#include <stdint.h>
#include <math.h>

#define KB 512
#define KT 2048
#define KS 16
#define KPD 4
#define QT 512          // timesteps per quarter
#define NQ (KT / QT)
#define HRS 168         // f16 per H row
#define QSTR 515        // u32 row stride for QR/zs (odd; capacity 512)

typedef _Float16 f16;
typedef _Float16 f16x8 __attribute__((ext_vector_type(8)));
typedef float f32x4 __attribute__((ext_vector_type(4)));

#define MFMA16(A, B, C) __builtin_amdgcn_mfma_f32_16x16x32_f16(A, B, C, 0, 0, 0)

__device__ __forceinline__ float softplus_f(float x) {
    float ax = fabsf(x);
    float e  = __expf(-ax);
    return fmaxf(x, 0.0f) + __logf(1.0f + e);
}
__device__ __forceinline__ float sigmoid_f(float x) {
    return __builtin_amdgcn_rcpf(1.0f + __expf(-x));
}
__device__ __forceinline__ float h2f_lo(uint32_t w) {
    return __half2float(__ushort_as_half((unsigned short)(w & 0xffffu)));
}
__device__ __forceinline__ float h2f_hi(uint32_t w) {
    return __half2float(__ushort_as_half((unsigned short)(w >> 16)));
}
__device__ __forceinline__ f16x8 zero8() {
    f16x8 v;
#pragma unroll
    for (int i = 0; i < 8; ++i) v[i] = (f16)0;
    return v;
}
// bank-spreading bijective time swizzle (within a 512-step quarter)
__device__ __forceinline__ int spos(int t) { return t ^ ((t >> 5) & 31); }

// ---------------- fused kernel: block = one b; MFMA MLP + parallel scan per quarter ----------------
__global__ __launch_bounds__(512, 2) void kalman_one(
    const float* __restrict__ z, const float* __restrict__ p,
    const float* __restrict__ mu0, const float* __restrict__ P0,
    const float* __restrict__ Wq1, const float* __restrict__ bq1,
    const float* __restrict__ Wq2, const float* __restrict__ bq2,
    const float* __restrict__ Wr1, const float* __restrict__ br1,
    const float* __restrict__ Wr2, const float* __restrict__ br2,
    const float* __restrict__ Wg1, const float* __restrict__ bg1,
    const float* __restrict__ Wg2, const float* __restrict__ bg2,
    float* __restrict__ out)
{
    __shared__ __align__(16) uint32_t QRl[KS * QSTR];     // 32960 B, [s][spos(t)]
    __shared__ __align__(16) float    Gl[QT];             //  2048 B, [spos(t)]
    __shared__ __align__(16) uint32_t Ubuf[10752];        // 43008 B: H slices (A) / zs (B-D)

    const int tid = threadIdx.x;
    const int wv = tid >> 6;
    const int l = tid & 63;
    const int g = l >> 4;
    const int c = l & 15;
    const int b = blockIdx.x;

    f16* __restrict__ Hw = reinterpret_cast<f16*>(Ubuf) + wv * (KS * HRS);
    float* __restrict__ zs = reinterpret_cast<float*>(Ubuf);   // [s][spos(t)] stride QSTR

    const float* __restrict__ zb = z + (size_t)b * KT * KS;
    const float* __restrict__ pb = p + (size_t)b * KT * KPD;
    float* __restrict__ ob = out + (size_t)b * KT * KS;

    // ---- const A-frags: W1cat^T ----
    f16x8 fA1[10];
#pragma unroll
    for (int m = 0; m < 10; ++m) {
        const float* W = (m < 4) ? (Wq1 + m * 16)
                       : (m < 8) ? (Wr1 + (m - 4) * 16)
                                 : (Wg1 + (m - 8) * 16);
        const int ld = (m < 8) ? 64 : 32;
        float w0 = W[0 * ld + c], w1 = W[1 * ld + c],
              w2 = W[2 * ld + c], w3 = W[3 * ld + c];
        f16x8 a = zero8();
        if (g == 0) { a[0] = (f16)w0; a[1] = (f16)w1; a[2] = (f16)w2; a[3] = (f16)w3; }
        fA1[m] = a;
    }
    // ---- const A-frags: W2cat^T ----
    f16x8 fA2[5];
#pragma unroll
    for (int i = 0; i < 4; ++i) {
        const float* W = (i < 2) ? Wq2 : Wr2;
        const int kb = (i & 1) * 32;
        f16x8 a;
#pragma unroll
        for (int j = 0; j < 8; ++j) a[j] = (f16)W[(kb + g * 8 + j) * 16 + c];
        fA2[i] = a;
    }
    {
        f16x8 a = zero8();
        if (c == 0) {
#pragma unroll
            for (int j = 0; j < 8; ++j) a[j] = (f16)Wg2[g * 8 + j];
        }
        fA2[4] = a;
    }
    const float bQ0 = bq2[g * 4 + 0], bQ1 = bq2[g * 4 + 1],
                bQ2 = bq2[g * 4 + 2], bQ3 = bq2[g * 4 + 3];
    const float bR0 = br2[g * 4 + 0], bR1 = br2[g * 4 + 1],
                bR2 = br2[g * 4 + 2], bR3 = br2[g * 4 + 3];
    const float bG = bg2[0];

    // ---- scan carries: wave wv owns chains s=wv and s=wv+8 ----
    float muA = mu0[b * KS + wv],     PA = P0[b * KS + wv];
    float muB = mu0[b * KS + wv + 8], PB = P0[b * KS + wv + 8];

    auto scan_s = [&](int s, float& mu_q, float& P_q) {
        uint32_t qr[8];
        const uint32_t* qrow = QRl + (size_t)s * QSTR;
        float zvv[8], gvv[8];
#pragma unroll
        for (int i = 0; i < 8; ++i) {
            const int ps = spos(l * 8 + i);
            qr[i] = qrow[ps];
            zvv[i] = zs[s * QSTR + ps];
            gvv[i] = Gl[ps];
        }
        float c00 = 1.f, c01 = 0.f, c10 = 0.f, c11 = 1.f;
#pragma unroll
        for (int i = 0; i < 8; ++i) {
            float Q = h2f_lo(qr[i]), R = h2f_hi(qr[i]);
            float ta = fmaf(Q, c10, c00);
            float tb = fmaf(Q, c11, c01);
            float n10 = fmaf(Q + R, c10, c00);
            float n11 = fmaf(Q + R, c11, c01);
            c00 = R * ta; c01 = R * tb; c10 = n10; c11 = n11;
        }
        float rn = __builtin_amdgcn_rcpf(c11);
        float ma = c00 * rn, mb = c01 * rn, mc = c10 * rn;
#pragma unroll
        for (int r = 0; r < 6; ++r) {
            const int d = 1 << r;
            float pa = __shfl_up(ma, d);
            float pbv = __shfl_up(mb, d);
            float pc = __shfl_up(mc, d);
            float na = fmaf(ma, pa, mb * pc);
            float nb = fmaf(ma, pbv, mb);
            float nc = fmaf(mc, pa, pc);
            float nd = fmaf(mc, pbv, 1.f);
            float rr = __builtin_amdgcn_rcpf(nd);
            bool act = (l >= d);
            ma = act ? na * rr : ma;
            mb = act ? nb * rr : mb;
            mc = act ? nc * rr : mc;
        }
        float ea = __shfl_up(ma, 1);
        float eb = __shfl_up(mb, 1);
        float ec = __shfl_up(mc, 1);
        if (l == 0) { ea = 1.f; eb = 0.f; ec = 0.f; }
        float P = fmaf(ea, P_q, eb) * __builtin_amdgcn_rcpf(fmaf(ec, P_q, 1.f));

        float av[8], bw[8];
        float A = 1.f, Bv = 0.f;
#pragma unroll
        for (int i = 0; i < 8; ++i) {
            float Q = h2f_lo(qr[i]), R = h2f_hi(qr[i]);
            float Pp = P + Q;
            float K0 = Pp * __builtin_amdgcn_rcpf(Pp + R);
            float Kk = __builtin_amdgcn_fmed3f(K0, 1e-6f, 0.95f);
            float gk = gvv[i] * Kk;
            av[i] = 1.f - gk;
            bw[i] = gk * zvv[i];
            P = fmaf(-Kk, Pp, Pp);
            A = A * av[i];
            Bv = fmaf(av[i], Bv, bw[i]);
        }
        float P_end = __shfl(P, 63);
#pragma unroll
        for (int r = 0; r < 6; ++r) {
            const int d = 1 << r;
            float pA = __shfl_up(A, d);
            float pB = __shfl_up(Bv, d);
            float nA = A * pA;
            float nB = fmaf(A, pB, Bv);
            bool act = (l >= d);
            A  = act ? nA : A;
            Bv = act ? nB : Bv;
        }
        float eA = __shfl_up(A, 1);
        float eB = __shfl_up(Bv, 1);
        if (l == 0) { eA = 1.f; eB = 0.f; }
        float mu = fmaf(eA, mu_q, eB);
#pragma unroll
        for (int i = 0; i < 8; ++i) {
            mu = fmaf(av[i], mu, bw[i]);
            zs[s * QSTR + spos(l * 8 + i)] = mu;   // overwrite z with mu
        }
        mu_q = __shfl(mu, 63);
        P_q = P_end;
    };

    for (int q = 0; q < NQ; ++q) {
        // ============ phase A: MLP (wave wv -> quarter rows wv*64..+63) ============
        {
            const int trow = q * QT + wv * 64;
            const float4 pv = *reinterpret_cast<const float4*>(pb + (size_t)(trow + l) * KPD);

            f16x8 fBP[4];
#pragma unroll
            for (int n = 0; n < 4; ++n) {
                const int src = n * 16 + c;
                float x = __shfl(pv.x, src);
                float y = __shfl(pv.y, src);
                float zz = __shfl(pv.z, src);
                float w = __shfl(pv.w, src);
                f16x8 v = zero8();
                if (g == 0) { v[0] = (f16)x; v[1] = (f16)y; v[2] = (f16)zz; v[3] = (f16)w; }
                fBP[n] = v;
            }

#pragma unroll
            for (int n = 0; n < 4; ++n) {
#pragma unroll
                for (int m = 0; m < 10; ++m) {
                    const float* bs = (m < 4) ? (bq1 + m * 16)
                                    : (m < 8) ? (br1 + (m - 4) * 16)
                                              : (bg1 + (m - 8) * 16);
                    f32x4 acc;
                    acc[0] = bs[g * 4 + 0]; acc[1] = bs[g * 4 + 1];
                    acc[2] = bs[g * 4 + 2]; acc[3] = bs[g * 4 + 3];
                    acc = MFMA16(fA1[m], fBP[n], acc);
                    auto h01 = __builtin_amdgcn_cvt_pkrtz(fmaxf(acc[0], 0.f), fmaxf(acc[1], 0.f));
                    auto h23 = __builtin_amdgcn_cvt_pkrtz(fmaxf(acc[2], 0.f), fmaxf(acc[3], 0.f));
                    uint32_t w0, w1;
                    __builtin_memcpy(&w0, &h01, 4);
                    __builtin_memcpy(&w1, &h23, 4);
                    *reinterpret_cast<uint32_t*>(&Hw[c * HRS + m * 16 + g * 4 + 0]) = w0;
                    *reinterpret_cast<uint32_t*>(&Hw[c * HRS + m * 16 + g * 4 + 2]) = w1;
                }
                f16x8 fb0 = *reinterpret_cast<const f16x8*>(&Hw[c * HRS + 0 * 32 + g * 8]);
                f16x8 fb1 = *reinterpret_cast<const f16x8*>(&Hw[c * HRS + 1 * 32 + g * 8]);
                f16x8 fb2 = *reinterpret_cast<const f16x8*>(&Hw[c * HRS + 2 * 32 + g * 8]);
                f16x8 fb3 = *reinterpret_cast<const f16x8*>(&Hw[c * HRS + 3 * 32 + g * 8]);
                f16x8 fb4 = *reinterpret_cast<const f16x8*>(&Hw[c * HRS + 4 * 32 + g * 8]);

                f32x4 aq; aq[0] = bQ0; aq[1] = bQ1; aq[2] = bQ2; aq[3] = bQ3;
                aq = MFMA16(fA2[0], fb0, aq);
                aq = MFMA16(fA2[1], fb1, aq);
                f32x4 ar; ar[0] = bR0; ar[1] = bR1; ar[2] = bR2; ar[3] = bR3;
                ar = MFMA16(fA2[2], fb2, ar);
                ar = MFMA16(fA2[3], fb3, ar);
                f32x4 ag; ag[0] = 0.f; ag[1] = 0.f; ag[2] = 0.f; ag[3] = 0.f;
                ag = MFMA16(fA2[4], fb4, ag);

                const int tt = wv * 64 + n * 16 + c;     // time within quarter
                const int ps = spos(tt);
#pragma unroll
                for (int i = 0; i < 4; ++i) {
                    float Qv = softplus_f(aq[i]) + 1e-8f;
                    float Rv = softplus_f(ar[i]) + 1e-8f;
                    auto pk = __builtin_amdgcn_cvt_pkrtz(Qv, Rv);
                    uint32_t w; __builtin_memcpy(&w, &pk, 4);
                    QRl[(size_t)(g * 4 + i) * QSTR + ps] = w;
                }
                if (g == 0)
                    Gl[ps] = sigmoid_f(ag[0] + bG);
            }
        }
        __syncthreads();   // QR/Gl ready; H region dead -> reusable as zs

        // ============ phase B: stage z quarter into zs [s][spos(t)] ============
        {
            const float4* zq = reinterpret_cast<const float4*>(zb + (size_t)q * QT * KS);
#pragma unroll
            for (int v = 0; v < 4; ++v) {
                int k = tid + 512 * v;
                float4 w = zq[k];
                int t = k >> 2, s0 = (k & 3) << 2;
                const int ps = spos(t);
                zs[(s0 + 0) * QSTR + ps] = w.x;
                zs[(s0 + 1) * QSTR + ps] = w.y;
                zs[(s0 + 2) * QSTR + ps] = w.z;
                zs[(s0 + 3) * QSTR + ps] = w.w;
            }
        }
        __syncthreads();

        // ============ phase C: chunk scans (2 s-chains per wave) ============
        scan_s(wv, muA, PA);
        scan_s(wv + 8, muB, PB);
        __syncthreads();

        // ============ phase D: coalesced out store ============
        {
            float* od = ob + (size_t)q * QT * KS;
#pragma unroll
            for (int v = 0; v < 4; ++v) {
                int k = tid + 512 * v;
                int t = k >> 2, s0 = (k & 3) << 2;
                const int ps = spos(t);
                float4 w;
                w.x = zs[(s0 + 0) * QSTR + ps];
                w.y = zs[(s0 + 1) * QSTR + ps];
                w.z = zs[(s0 + 2) * QSTR + ps];
                w.w = zs[(s0 + 3) * QSTR + ps];
                *reinterpret_cast<float4*>(od + 4 * (size_t)k) = w;
            }
        }
        __syncthreads();   // zs/H region reused next quarter
    }
}

// ---------------- launcher ----------------
extern "C" void kernel_launch(void* const* d_in, const int* in_sizes, int n_in,
                              void* d_out, int out_size, void* d_ws, size_t ws_size,
                              hipStream_t stream) {
    const float* z   = (const float*)d_in[0];
    const float* p   = (const float*)d_in[1];
    const float* mu0 = (const float*)d_in[2];
    const float* P0  = (const float*)d_in[3];
    const float* Wq1 = (const float*)d_in[4];
    const float* bq1 = (const float*)d_in[5];
    const float* Wq2 = (const float*)d_in[6];
    const float* bq2 = (const float*)d_in[7];
    const float* Wr1 = (const float*)d_in[8];
    const float* br1 = (const float*)d_in[9];
    const float* Wr2 = (const float*)d_in[10];
    const float* br2 = (const float*)d_in[11];
    const float* Wg1 = (const float*)d_in[12];
    const float* bg1 = (const float*)d_in[13];
    const float* Wg2 = (const float*)d_in[14];
    const float* bg2 = (const float*)d_in[15];
    float* out = (float*)d_out;

    hipLaunchKernelGGL(kalman_one, dim3(KB), dim3(512), 0, stream,
                       z, p, mu0, P0, Wq1, bq1, Wq2, bq2,
                       Wr1, br1, Wr2, br2, Wg1, bg1, Wg2, bg2, out);
}